// Round 3
// baseline (5710.760 us; speedup 1.0000x reference)
//
#include <hip/hip_runtime.h>

#define V_NODES 30000
#define DIM 300
#define NE 960000
#define NDOCS 8192
#define DLEN 64
#define CM 10000   // QKV chunk rows (30000 = 3*10000)

typedef float f32x4 __attribute__((ext_vector_type(4)));
typedef short bf16x8 __attribute__((ext_vector_type(8)));

// float -> bf16 (RTNE), as bit pattern
__device__ __forceinline__ unsigned short f2bf(float x) {
    unsigned u = __float_as_uint(x);
    unsigned r = (u + 0x7FFFu + ((u >> 16) & 1u)) >> 16;
    return (unsigned short)r;
}
__device__ __forceinline__ float bf2f(unsigned short h) {
    return __uint_as_float(((unsigned)h) << 16);
}

// ---------------------------------------------------------------------------
// MFMA split-bf16 GEMM: C[M,N] = A[M,K] @ B[K,N]  (fp32 in/out, ~fp32 accuracy)
// A,B decomposed per-element into hi+lo bf16; per frag-pair 3 MFMAs:
//   acc += Ah*Bl; acc += Al*Bh; acc += Ah*Bh   (error ~2^-17 relative)
// Tile: BM=128, BN=64, BK=32; 256 thr = 4 waves (2x2), wave tile 64x32 of
// 16x16x32 fragments.  Epilogue: v = acc*rowscale[r] + bias[c] + rowv[r]*colv[c]
// ---------------------------------------------------------------------------
#define GBM 128
#define GBN 64
#define GBK 32
#define LDK 40   // GBK + 8 shorts pad (80B row stride, keeps 16B alignment)

__global__ __launch_bounds__(256) void mgemm_kernel(
    const float* __restrict__ A, const float* __restrict__ B, float* __restrict__ C,
    int M, int N, int K, const float* __restrict__ bias, const float* __restrict__ rowscale,
    const float* __restrict__ rowv, const float* __restrict__ colv)
{
    __shared__ short As_hi[GBM * LDK];
    __shared__ short As_lo[GBM * LDK];
    __shared__ short Bs_hi[GBN * LDK];
    __shared__ short Bs_lo[GBN * LDK];

    const int tid = threadIdx.x;
    const int bm = blockIdx.y * GBM, bn = blockIdx.x * GBN;

    const int l  = tid & 63;
    const int w  = tid >> 6;
    const int wr = w >> 1, wc = w & 1;    // wave grid 2x2
    const int lr = l & 15, lk = l >> 4;   // frag row/col, k-group

    // A staging: row = tid>>1, 16 consecutive k per thread
    const int s_arow = tid >> 1;
    const int s_ak0  = (tid & 1) * 16;
    // B staging: col = tid&63, 8 consecutive k per thread
    const int s_bcol = tid & 63;
    const int s_bk0  = (tid >> 6) * 8;

    f32x4 acc[4][2];
#pragma unroll
    for (int m = 0; m < 4; m++)
#pragma unroll
        for (int n = 0; n < 2; n++) acc[m][n] = (f32x4){0.f, 0.f, 0.f, 0.f};

    const int gr = bm + s_arow;
    const bool grv = gr < M;
    const int gc = bn + s_bcol;
    const bool gcv = gc < N;

    for (int k0 = 0; k0 < K; k0 += GBK) {
        // ---- stage A tile (rows x k), split hi/lo ----
        {
            const float* ap = A + (size_t)gr * K + k0 + s_ak0;
#pragma unroll
            for (int j = 0; j < 16; j++) {
                int kk = s_ak0 + j;
                float x = (grv && (k0 + kk) < K) ? ap[j] : 0.f;
                unsigned short h = f2bf(x);
                unsigned short lo = f2bf(x - bf2f(h));
                As_hi[s_arow * LDK + kk] = (short)h;
                As_lo[s_arow * LDK + kk] = (short)lo;
            }
        }
        // ---- stage B tile transposed (col x k), split hi/lo ----
        {
#pragma unroll
            for (int j = 0; j < 8; j++) {
                int kk = s_bk0 + j;
                float x = (gcv && (k0 + kk) < K) ? B[(size_t)(k0 + kk) * N + gc] : 0.f;
                unsigned short h = f2bf(x);
                unsigned short lo = f2bf(x - bf2f(h));
                Bs_hi[s_bcol * LDK + kk] = (short)h;
                Bs_lo[s_bcol * LDK + kk] = (short)lo;
            }
        }
        __syncthreads();

        // ---- fragments + MFMA ----
        bf16x8 ah[4], al[4], bh[2], bl[2];
#pragma unroll
        for (int m = 0; m < 4; m++) {
            int row = wr * 64 + m * 16 + lr;
            ah[m] = *(const bf16x8*)&As_hi[row * LDK + lk * 8];
            al[m] = *(const bf16x8*)&As_lo[row * LDK + lk * 8];
        }
#pragma unroll
        for (int n = 0; n < 2; n++) {
            int col = wc * 32 + n * 16 + lr;
            bh[n] = *(const bf16x8*)&Bs_hi[col * LDK + lk * 8];
            bl[n] = *(const bf16x8*)&Bs_lo[col * LDK + lk * 8];
        }
#pragma unroll
        for (int m = 0; m < 4; m++)
#pragma unroll
            for (int n = 0; n < 2; n++) {
                acc[m][n] = __builtin_amdgcn_mfma_f32_16x16x32_bf16(ah[m], bl[n], acc[m][n], 0, 0, 0);
                acc[m][n] = __builtin_amdgcn_mfma_f32_16x16x32_bf16(al[m], bh[n], acc[m][n], 0, 0, 0);
                acc[m][n] = __builtin_amdgcn_mfma_f32_16x16x32_bf16(ah[m], bh[n], acc[m][n], 0, 0, 0);
            }
        __syncthreads();
    }

    // ---- epilogue: C/D layout col=lane&15, row=(lane>>4)*4+j ----
#pragma unroll
    for (int n = 0; n < 2; n++) {
        int col = bn + wc * 32 + n * 16 + lr;
        if (col >= N) continue;
        float bcol = bias ? bias[col] : 0.f;
        float cv = colv ? colv[col] : 0.f;
#pragma unroll
        for (int m = 0; m < 4; m++) {
#pragma unroll
            for (int j = 0; j < 4; j++) {
                int row = bm + wr * 64 + m * 16 + lk * 4 + j;
                if (row >= M) continue;
                float v = acc[m][n][j];
                if (rowscale) v *= rowscale[row];
                v += bcol;
                if (rowv) v += rowv[row] * cv;
                C[(size_t)row * N + col] = v;
            }
        }
    }
}

// ---------------------------------------------------------------------------
// Graph kernels
// ---------------------------------------------------------------------------
__global__ void degree_kernel(const int* __restrict__ src, const int* __restrict__ dst,
                              int* __restrict__ dout, int* __restrict__ din, int n)
{
    int e = blockIdx.x * blockDim.x + threadIdx.x;
    if (e >= n) return;
    atomicAdd(&dout[src[e]], 1);
    atomicAdd(&din[dst[e]], 1);
}

__global__ void nsnd_kernel(const int* __restrict__ dout, const int* __restrict__ din,
                            float* __restrict__ ns, float* __restrict__ nd, int n)
{
    int i = blockIdx.x * blockDim.x + threadIdx.x;
    if (i >= n) return;
    ns[i] = rsqrtf((float)max(dout[i], 1));
    nd[i] = rsqrtf((float)max(din[i], 1));
}

// single-block scan -> exclusive row_ptr (row_ptr[0]=0, row_ptr[n]=total)
__global__ void scan_kernel(const int* __restrict__ deg, int* __restrict__ row_ptr, int n)
{
    __shared__ int sdata[1024];
    __shared__ int carry;
    if (threadIdx.x == 0) { carry = 0; row_ptr[0] = 0; }
    __syncthreads();
    for (int base = 0; base < n; base += 1024) {
        int i = base + (int)threadIdx.x;
        int v = (i < n) ? deg[i] : 0;
        sdata[threadIdx.x] = v;
        __syncthreads();
        for (int off = 1; off < 1024; off <<= 1) {
            int t = (threadIdx.x >= (unsigned)off) ? sdata[threadIdx.x - off] : 0;
            __syncthreads();
            sdata[threadIdx.x] += t;
            __syncthreads();
        }
        if (i < n) row_ptr[i + 1] = carry + sdata[threadIdx.x];
        __syncthreads();
        if (threadIdx.x == 1023) carry += sdata[1023];
        __syncthreads();
    }
}

__global__ void fill_kernel(const int* __restrict__ src, const int* __restrict__ dst,
                            const int* __restrict__ row_ptr, int* __restrict__ cursor,
                            int* __restrict__ col, int n)
{
    int e = blockIdx.x * blockDim.x + threadIdx.x;
    if (e >= n) return;
    int d = dst[e];
    int p = atomicAdd(&cursor[d], 1);
    col[row_ptr[d] + p] = src[e];
}

// out[v,:] = (sum over in-edges of hs[src,:]) * nd[v] + bias (+ residual)
__global__ __launch_bounds__(256) void agg_kernel(
    const float* __restrict__ hs, const int* __restrict__ row_ptr, const int* __restrict__ col,
    const float* __restrict__ ndv, const float* __restrict__ bias,
    const float* __restrict__ residual, float* __restrict__ out)
{
    int v = blockIdx.x;
    int t = threadIdx.x;
    int beg = row_ptr[v], end = row_ptr[v + 1];
    float a0 = 0.f, a1 = 0.f;
    for (int e = beg; e < end; e++) {
        int s = col[e];
        const float* r = hs + (size_t)s * DIM;
        a0 += r[t];
        if (t < DIM - 256) a1 += r[t + 256];
    }
    float nv = ndv[v];
    float* o = out + (size_t)v * DIM;
    float r0 = a0 * nv + bias[t];
    if (residual) r0 += residual[(size_t)v * DIM + t];
    o[t] = r0;
    if (t < DIM - 256) {
        float r1 = a1 * nv + bias[t + 256];
        if (residual) r1 += residual[(size_t)v * DIM + t + 256];
        o[t + 256] = r1;
    }
}

// ---------------------------------------------------------------------------
// 30-head attention over 3 view positions, folded with mean over q-positions.
// Q/K/V buffers: [3][cm][DIM].  Writes om rows [r0, r0+cm).
// ---------------------------------------------------------------------------
__global__ __launch_bounds__(256) void attn_kernel(
    const float* __restrict__ Qb, const float* __restrict__ Kb, const float* __restrict__ Vb,
    float* __restrict__ om, int cm, int r0)
{
    int t = blockIdx.x * 256 + threadIdx.x;
    if (t >= cm * 30) return;
    int i = t / 30, h = t - i * 30;
    int off = h * 10;
    float q[3][10], k[3][10], v[3][10];
#pragma unroll
    for (int s = 0; s < 3; s++) {
        const float* qp = Qb + ((size_t)s * cm + i) * DIM + off;
        const float* kp = Kb + ((size_t)s * cm + i) * DIM + off;
        const float* vp = Vb + ((size_t)s * cm + i) * DIM + off;
#pragma unroll
        for (int d = 0; d < 10; d++) { q[s][d] = qp[d]; k[s][d] = kp[d]; v[s][d] = vp[d]; }
    }
    const float scale = 0.31622776601683794f;  // 1/sqrt(10)
    float w[3] = {0.f, 0.f, 0.f};
#pragma unroll
    for (int qi = 0; qi < 3; qi++) {
        float sc[3];
#pragma unroll
        for (int ki = 0; ki < 3; ki++) {
            float s_ = 0.f;
#pragma unroll
            for (int d = 0; d < 10; d++) s_ = fmaf(q[qi][d], k[ki][d], s_);
            sc[ki] = s_ * scale;
        }
        float m = fmaxf(sc[0], fmaxf(sc[1], sc[2]));
        float e0 = expf(sc[0] - m), e1 = expf(sc[1] - m), e2 = expf(sc[2] - m);
        float inv = 1.f / (e0 + e1 + e2);
        w[0] += e0 * inv; w[1] += e1 * inv; w[2] += e2 * inv;
    }
    float* op = om + (size_t)(r0 + i) * DIM + off;
#pragma unroll
    for (int d = 0; d < 10; d++)
        op[d] = (w[0] * v[0][d] + w[1] * v[1][d] + w[2] * v[2][d]) * (1.f / 3.f);
}

// DM[d,:] = (1/64) * sum over valid tokens of om[idx,:];  DC[d] = cnt/64
__global__ __launch_bounds__(256) void docmean_kernel(
    const float* __restrict__ om, const int* __restrict__ adj,
    float* __restrict__ DM, float* __restrict__ DC)
{
    int d = blockIdx.x;
    int t = threadIdx.x;
    float a0 = 0.f, a1 = 0.f;
    int cnt = 0;
    for (int l = 0; l < DLEN; l++) {
        int idx = adj[d * DLEN + l];
        if (idx < V_NODES) {
            cnt++;
            const float* r = om + (size_t)idx * DIM;
            a0 += r[t];
            if (t < DIM - 256) a1 += r[t + 256];
        }
    }
    DM[(size_t)d * DIM + t] = a0 * (1.f / 64.f);
    if (t < DIM - 256) DM[(size_t)d * DIM + t + 256] = a1 * (1.f / 64.f);
    if (t == 0) DC[d] = (float)cnt * (1.f / 64.f);
}

// ---------------------------------------------------------------------------
extern "C" void kernel_launch(void* const* d_in, const int* in_sizes, int n_in,
                              void* d_out, int out_size, void* d_ws, size_t ws_size,
                              hipStream_t stream)
{
    const int* adj = (const int*)d_in[0];
    const int* srcs[3] = {(const int*)d_in[1], (const int*)d_in[3], (const int*)d_in[5]};
    const int* dsts[3] = {(const int*)d_in[2], (const int*)d_in[4], (const int*)d_in[6]};
    const float* emb = (const float*)d_in[8];
    const float* W1[3] = {(const float*)d_in[9],  (const float*)d_in[13], (const float*)d_in[17]};
    const float* b1[3] = {(const float*)d_in[10], (const float*)d_in[14], (const float*)d_in[18]};
    const float* W2[3] = {(const float*)d_in[11], (const float*)d_in[15], (const float*)d_in[19]};
    const float* b2[3] = {(const float*)d_in[12], (const float*)d_in[16], (const float*)d_in[20]};
    const float* Wq = (const float*)d_in[21], *bq = (const float*)d_in[22];
    const float* Wk = (const float*)d_in[23], *bk = (const float*)d_in[24];
    const float* Wv = (const float*)d_in[25], *bv = (const float*)d_in[26];
    const float* Wo = (const float*)d_in[27], *bo = (const float*)d_in[28];
    const float* Wd = (const float*)d_in[29], *bd = (const float*)d_in[30];
    const float* Wfc = (const float*)d_in[31], *bfc = (const float*)d_in[32];
    float* out = (float*)d_out;

    // ---- workspace carve ----
    char* p = (char*)d_ws;
    auto alloc = [&](size_t bytes) { void* r = (void*)p; p += (bytes + 255) & ~(size_t)255; return r; };
    float* ns  = (float*)alloc(V_NODES * 4);
    float* nd  = (float*)alloc(V_NODES * 4);
    int* ibase = (int*)alloc(3 * V_NODES * 4);   // deg_out | deg_in | cursor
    int* deg0 = ibase, *deg1 = ibase + V_NODES, *cursor = ibase + 2 * V_NODES;
    int* row_ptr = (int*)alloc((V_NODES + 1) * 4);
    int* col     = (int*)alloc(NE * 4);
    float* Wdf   = (float*)alloc(300 * 20 * 4);
    float* Wcomb = (float*)alloc(300 * 20 * 4);
    float* v1    = (float*)alloc(20 * 4);
    float* v2    = (float*)alloc(20 * 4);
    float* T1 = (float*)alloc((size_t)V_NODES * DIM * 4);
    float* T2 = (float*)alloc((size_t)V_NODES * DIM * 4);
    float* Bv[3];
    for (int i = 0; i < 3; i++) Bv[i] = (float*)alloc((size_t)V_NODES * DIM * 4);
    float* Kb = (float*)alloc((size_t)3 * CM * DIM * 4);
    float* Vb = (float*)alloc((size_t)3 * CM * DIM * 4);
    float* Qb = T2;                 // T2 free during MHA phase (3*CM*DIM == V*DIM)
    float* DM = Bv[0];              // [NDOCS, DIM]  (Bv free after MHA)
    float* DC = Bv[1];              // [NDOCS]

    auto gemm = [&](const float* A, const float* B, float* C, int M, int N, int K,
                    const float* bias, const float* rowscale,
                    const float* rowv = nullptr, const float* colv = nullptr) {
        dim3 grid((N + GBN - 1) / GBN, (M + GBM - 1) / GBM);
        hipLaunchKernelGGL(mgemm_kernel, grid, dim3(256), 0, stream,
                           A, B, C, M, N, K, bias, rowscale, rowv, colv);
    };

    const int EB = (NE + 255) / 256;
    const int VB = (V_NODES + 255) / 256;

    // ---- precompute folded tail matrices (tiny GEMMs) ----
    gemm(Wd, Wfc, Wdf, DIM, 20, DIM, nullptr, nullptr);        // Wdf = Wd@Wfc   [300,20]
    gemm(Wo, Wdf, Wcomb, DIM, 20, DIM, nullptr, nullptr);      // Wcomb = Wo@Wdf [300,20]
    gemm(bo, Wdf, v1, 1, 20, DIM, nullptr, nullptr);           // v1 = bo@Wdf    [20]
    gemm(bd, Wfc, v2, 1, 20, DIM, bfc, nullptr);               // v2 = bd@Wfc+bfc[20]

    // ---- three GCN branches ----
    for (int br = 0; br < 3; br++) {
        hipMemsetAsync(ibase, 0, (size_t)3 * V_NODES * 4, stream);
        hipLaunchKernelGGL(degree_kernel, dim3(EB), dim3(256), 0, stream, srcs[br], dsts[br], deg0, deg1, NE);
        hipLaunchKernelGGL(nsnd_kernel, dim3(VB), dim3(256), 0, stream, deg0, deg1, ns, nd, V_NODES);
        hipLaunchKernelGGL(scan_kernel, dim3(1), dim3(1024), 0, stream, deg1, row_ptr, V_NODES);
        hipLaunchKernelGGL(fill_kernel, dim3(EB), dim3(256), 0, stream, srcs[br], dsts[br], row_ptr, cursor, col, NE);
        // layer 1:  T2 = agg(emb@W1 * ns) * nd + b1
        gemm(emb, W1[br], T1, V_NODES, DIM, DIM, nullptr, ns);
        hipLaunchKernelGGL(agg_kernel, dim3(V_NODES), dim3(256), 0, stream, T1, row_ptr, col, nd, b1[br], (const float*)nullptr, T2);
        // layer 2 (+ residual emb):  Bv = agg(T2@W2 * ns) * nd + b2 + emb
        gemm(T2, W2[br], T1, V_NODES, DIM, DIM, nullptr, ns);
        hipLaunchKernelGGL(agg_kernel, dim3(V_NODES), dim3(256), 0, stream, T1, row_ptr, col, nd, b2[br], emb, Bv[br]);
    }

    // ---- MHA pool over the 3 views (chunked), mean-pooled output -> T1 ----
    for (int c = 0; c < V_NODES / CM; c++) {
        int r0 = c * CM;
        for (int s = 0; s < 3; s++) {
            const float* x = Bv[s] + (size_t)r0 * DIM;
            gemm(x, Wq, Qb + (size_t)s * CM * DIM, CM, DIM, DIM, bq, nullptr);
            gemm(x, Wk, Kb + (size_t)s * CM * DIM, CM, DIM, DIM, bk, nullptr);
            gemm(x, Wv, Vb + (size_t)s * CM * DIM, CM, DIM, DIM, bv, nullptr);
        }
        hipLaunchKernelGGL(attn_kernel, dim3((CM * 30 + 255) / 256), dim3(256), 0, stream, Qb, Kb, Vb, T1, CM, r0);
    }

    // ---- doc pipeline (fully folded tail) ----
    hipLaunchKernelGGL(docmean_kernel, dim3(NDOCS), dim3(256), 0, stream, T1, adj, DM, DC);
    // out = DM @ Wcomb + DC*v1 + v2
    gemm(DM, Wcomb, out, NDOCS, 20, DIM, v2, nullptr, DC, v1);
}

// Round 6
// 3144.038 us; speedup vs baseline: 1.8164x; 1.8164x over previous
//
#include <hip/hip_runtime.h>

#define V_NODES 30000
#define DIM 300
#define KP 320            // padded K stride (shorts) for split bf16 planes
#define NE 960000
#define NDOCS 8192
#define DLEN 64
#define CM 6000           // QKV chunk rows (30000 = 5*6000)
#define NQKV 900

typedef float f32x4 __attribute__((ext_vector_type(4)));
typedef short bf16x8 __attribute__((ext_vector_type(8)));

// float -> bf16 (RTNE) bit pattern
__device__ __forceinline__ unsigned short f2bf(float x) {
    unsigned u = __float_as_uint(x);
    unsigned r = (u + 0x7FFFu + ((u >> 16) & 1u)) >> 16;
    return (unsigned short)r;
}
__device__ __forceinline__ float bf2f(unsigned short h) {
    return __uint_as_float(((unsigned)h) << 16);
}

// ---------------------------------------------------------------------------
// Split-bf16 MFMA GEMM.  A,B given as pre-split bf16 planes:
//   Ah/Al: [M][KP] row-major,  Bh/Bl: [N][KP] (i.e. B transposed), zero-padded
//   to KP in k.  C[M][ldc] fp32.  acc += Ah*Bl + Al*Bh + Ah*Bh  (~fp32 acc).
// Tile: 128x128, 256 thr = 4 waves (2x2), wave = 64x64 = 4x4 frags 16x16x32.
// LDS [plane][kslot][row][8] -> 16-lane frag reads are 256B contiguous
// (conflict-free); staging writes are b128 contiguous per wave.
// ---------------------------------------------------------------------------
#define GBM 128
#define GBN 128
#define GBK 32
#define KTILES (KP / GBK)   // 10

__global__ __launch_bounds__(256) void mgemm_kernel(
    const unsigned short* __restrict__ Ah, const unsigned short* __restrict__ Al,
    const unsigned short* __restrict__ Bh, const unsigned short* __restrict__ Bl,
    float* __restrict__ C, int M, int N, int ldc,
    const float* __restrict__ bias, const float* __restrict__ rowscale)
{
    __shared__ short As[2][4][GBM][8];   // [plane][kslot][row][8]
    __shared__ short Bs[2][4][GBN][8];

    const int tid = threadIdx.x;
    const int bm = blockIdx.y * GBM, bn = blockIdx.x * GBN;
    const int l = tid & 63, w = tid >> 6;
    const int wr = w >> 1, wc = w & 1;
    const int lk = l >> 4, lr = l & 15;

    const int srow = tid >> 1;           // staged row (A) / col (B)
    const int sc0  = (tid & 1) * 2;      // kslot pair base: 0 or 2

    const bool avld = (bm + srow) < M;
    const bool bvld = (bn + srow) < N;
    const unsigned short* apH = Ah + (size_t)(bm + srow) * KP + sc0 * 8;
    const unsigned short* apL = Al + (size_t)(bm + srow) * KP + sc0 * 8;
    const unsigned short* bpH = Bh + (size_t)(bn + srow) * KP + sc0 * 8;
    const unsigned short* bpL = Bl + (size_t)(bn + srow) * KP + sc0 * 8;

    f32x4 acc[4][4];
#pragma unroll
    for (int m = 0; m < 4; m++)
#pragma unroll
        for (int n = 0; n < 4; n++) acc[m][n] = (f32x4){0.f, 0.f, 0.f, 0.f};

    const bf16x8 zz = (bf16x8){0,0,0,0,0,0,0,0};

    for (int kt = 0; kt < KTILES; kt++) {
        const int k0 = kt * GBK;
        bf16x8 vah0 = avld ? *(const bf16x8*)(apH + k0)     : zz;
        bf16x8 vah1 = avld ? *(const bf16x8*)(apH + k0 + 8) : zz;
        bf16x8 val0 = avld ? *(const bf16x8*)(apL + k0)     : zz;
        bf16x8 val1 = avld ? *(const bf16x8*)(apL + k0 + 8) : zz;
        bf16x8 vbh0 = bvld ? *(const bf16x8*)(bpH + k0)     : zz;
        bf16x8 vbh1 = bvld ? *(const bf16x8*)(bpH + k0 + 8) : zz;
        bf16x8 vbl0 = bvld ? *(const bf16x8*)(bpL + k0)     : zz;
        bf16x8 vbl1 = bvld ? *(const bf16x8*)(bpL + k0 + 8) : zz;

        *(bf16x8*)&As[0][sc0    ][srow][0] = vah0;
        *(bf16x8*)&As[0][sc0 + 1][srow][0] = vah1;
        *(bf16x8*)&As[1][sc0    ][srow][0] = val0;
        *(bf16x8*)&As[1][sc0 + 1][srow][0] = val1;
        *(bf16x8*)&Bs[0][sc0    ][srow][0] = vbh0;
        *(bf16x8*)&Bs[0][sc0 + 1][srow][0] = vbh1;
        *(bf16x8*)&Bs[1][sc0    ][srow][0] = vbl0;
        *(bf16x8*)&Bs[1][sc0 + 1][srow][0] = vbl1;
        __syncthreads();

        bf16x8 ah[4], al[4], bh[4], bl[4];
#pragma unroll
        for (int m = 0; m < 4; m++) {
            int row = wr * 64 + m * 16 + lr;
            ah[m] = *(const bf16x8*)&As[0][lk][row][0];
            al[m] = *(const bf16x8*)&As[1][lk][row][0];
        }
#pragma unroll
        for (int n = 0; n < 4; n++) {
            int colr = wc * 64 + n * 16 + lr;
            bh[n] = *(const bf16x8*)&Bs[0][lk][colr][0];
            bl[n] = *(const bf16x8*)&Bs[1][lk][colr][0];
        }
#pragma unroll
        for (int m = 0; m < 4; m++)
#pragma unroll
            for (int n = 0; n < 4; n++) {
                acc[m][n] = __builtin_amdgcn_mfma_f32_16x16x32_bf16(ah[m], bl[n], acc[m][n], 0, 0, 0);
                acc[m][n] = __builtin_amdgcn_mfma_f32_16x16x32_bf16(al[m], bh[n], acc[m][n], 0, 0, 0);
                acc[m][n] = __builtin_amdgcn_mfma_f32_16x16x32_bf16(ah[m], bh[n], acc[m][n], 0, 0, 0);
            }
        __syncthreads();
    }

    // epilogue: C/D layout col=lane&15, row=(lane>>4)*4+j
#pragma unroll
    for (int n = 0; n < 4; n++) {
        int gcol = bn + wc * 64 + n * 16 + lr;
        if (gcol >= N) continue;
        float bc = bias ? bias[gcol] : 0.f;
#pragma unroll
        for (int m = 0; m < 4; m++) {
            int rbase = bm + wr * 64 + m * 16 + lk * 4;
#pragma unroll
            for (int j = 0; j < 4; j++) {
                int grow = rbase + j;
                if (grow >= M) continue;
                float vv = acc[m][n][j];
                if (rowscale) vv *= rowscale[grow];
                C[(size_t)grow * ldc + gcol] = vv + bc;
            }
        }
    }
}

// ---------------------------------------------------------------------------
// fp32 fallback GEMM for tiny shapes (K % 20 == 0).
// epilogue: v = acc + bias[c] + rowv[r]*colv[c]
// ---------------------------------------------------------------------------
#define BM 128
#define BN 64
#define BK 20

__global__ __launch_bounds__(256) void sgemm_kernel(
    const float* __restrict__ A, const float* __restrict__ B, float* __restrict__ C,
    int M, int N, int K, const float* __restrict__ bias,
    const float* __restrict__ rowv, const float* __restrict__ colv)
{
    __shared__ float Asm[BK][BM + 4];
    __shared__ float Bsm[BK][BN + 4];
    const int tid = threadIdx.x;
    const int bm = blockIdx.y * BM, bn = blockIdx.x * BN;
    const int tx = tid & 15, ty = tid >> 4;

    float acc[8][4];
#pragma unroll
    for (int i = 0; i < 8; i++)
#pragma unroll
        for (int j = 0; j < 4; j++) acc[i][j] = 0.f;

    const int arow = tid >> 1;
    const int akk0 = (tid & 1) * 10;
    const int bnl  = tid & 63;
    const int bkr  = tid >> 6;

    for (int k0 = 0; k0 < K; k0 += BK) {
        {
            int gr = bm + arow;
            if (gr < M) {
                const float* ap = A + (size_t)gr * K + k0 + akk0;
#pragma unroll
                for (int j = 0; j < 10; j++) Asm[akk0 + j][arow] = ap[j];
            } else {
#pragma unroll
                for (int j = 0; j < 10; j++) Asm[akk0 + j][arow] = 0.f;
            }
        }
        {
            int gn = bn + bnl;
            bool nin = gn < N;
#pragma unroll
            for (int p = 0; p < 5; p++) {
                int kk = p * 4 + bkr;
                Bsm[kk][bnl] = nin ? B[(size_t)(k0 + kk) * N + gn] : 0.f;
            }
        }
        __syncthreads();
#pragma unroll
        for (int kk = 0; kk < BK; kk++) {
            float4 a0 = *(const float4*)&Asm[kk][ty * 8];
            float4 a1 = *(const float4*)&Asm[kk][ty * 8 + 4];
            float4 b  = *(const float4*)&Bsm[kk][tx * 4];
            float av[8] = {a0.x, a0.y, a0.z, a0.w, a1.x, a1.y, a1.z, a1.w};
            float bvv[4] = {b.x, b.y, b.z, b.w};
#pragma unroll
            for (int i = 0; i < 8; i++)
#pragma unroll
                for (int j = 0; j < 4; j++)
                    acc[i][j] = fmaf(av[i], bvv[j], acc[i][j]);
        }
        __syncthreads();
    }
#pragma unroll
    for (int i = 0; i < 8; i++) {
        int r = bm + ty * 8 + i;
        if (r >= M) continue;
        float rv = rowv ? rowv[r] : 0.f;
#pragma unroll
        for (int j = 0; j < 4; j++) {
            int c = bn + tx * 4 + j;
            if (c < N) {
                float v = acc[i][j];
                if (bias) v += bias[c];
                if (rowv) v += rv * colv[c];
                C[(size_t)r * N + c] = v;
            }
        }
    }
}

// ---------------------------------------------------------------------------
// Graph kernels
// ---------------------------------------------------------------------------
__global__ void degree_kernel(const int* __restrict__ src, const int* __restrict__ dst,
                              int* __restrict__ dout, int* __restrict__ din, int n)
{
    int e = blockIdx.x * blockDim.x + threadIdx.x;
    if (e >= n) return;
    atomicAdd(&dout[src[e]], 1);
    atomicAdd(&din[dst[e]], 1);
}

__global__ void nsnd_kernel(const int* __restrict__ dout, const int* __restrict__ din,
                            float* __restrict__ ns, float* __restrict__ nd,
                            float* __restrict__ ndns, int n)
{
    int i = blockIdx.x * blockDim.x + threadIdx.x;
    if (i >= n) return;
    float a = rsqrtf((float)max(dout[i], 1));
    float b = rsqrtf((float)max(din[i], 1));
    ns[i] = a; nd[i] = b; ndns[i] = a * b;
}

// single-block scan (1024 thr, each owns SCAN_E contiguous elements)
#define SCAN_E 30
__global__ void scan_kernel(const int* __restrict__ deg, int* __restrict__ row_ptr, int n)
{
    __shared__ int ssum[1024];
    const int t = threadIdx.x;
    const int base = t * SCAN_E;
    int loc[SCAN_E];
    int s = 0;
#pragma unroll
    for (int j = 0; j < SCAN_E; j++) {
        int i = base + j;
        int d = (i < n) ? deg[i] : 0;
        loc[j] = s; s += d;
    }
    ssum[t] = s;
    __syncthreads();
    for (int off = 1; off < 1024; off <<= 1) {
        int x = (t >= off) ? ssum[t - off] : 0;
        __syncthreads();
        ssum[t] += x;
        __syncthreads();
    }
    int carry = (t > 0) ? ssum[t - 1] : 0;
#pragma unroll
    for (int j = 0; j < SCAN_E; j++) {
        int i = base + j;
        if (i < n) row_ptr[i] = carry + loc[j];
    }
    if (t == 1023) row_ptr[n] = ssum[1023];
}

__global__ void fill_kernel(const int* __restrict__ src, const int* __restrict__ dst,
                            const int* __restrict__ row_ptr, int* __restrict__ cursor,
                            int* __restrict__ col, int n)
{
    int e = blockIdx.x * blockDim.x + threadIdx.x;
    if (e >= n) return;
    int d = dst[e];
    int p = atomicAdd(&cursor[d], 1);
    col[row_ptr[d] + p] = src[e];
}

// dhat[v] = nd[v] * sum_{in-edges} ns[src]
__global__ void dhat_kernel(const int* __restrict__ row_ptr, const int* __restrict__ col,
                            const float* __restrict__ ns, const float* __restrict__ nd,
                            float* __restrict__ dhat, int n)
{
    int v = blockIdx.x * blockDim.x + threadIdx.x;
    if (v >= n) return;
    float s = 0.f;
    int e0 = row_ptr[v], e1 = row_ptr[v + 1];
    for (int e = e0; e < e1; e++) s += ns[col[e]];
    dhat[v] = s * nd[v];
}

// ---------------------------------------------------------------------------
// Aggregation: out[v,:] = scalev[v]*(sum_in hs[src,:]) [+ bias] [+ r1row[v]*r1col]
//              [+ residual].  Output: fp32 (stride 300) OR split planes (KP).
// ---------------------------------------------------------------------------
__global__ __launch_bounds__(256) void agg_kernel(
    const float* __restrict__ hs, const int* __restrict__ row_ptr, const int* __restrict__ col,
    const float* __restrict__ scalev, const float* __restrict__ bias,
    const float* __restrict__ r1row, const float* __restrict__ r1col,
    const float* __restrict__ residual,
    float* __restrict__ outf,
    unsigned short* __restrict__ oh, unsigned short* __restrict__ ol)
{
    int v = blockIdx.x;
    int t = threadIdx.x;
    int beg = row_ptr[v], end = row_ptr[v + 1];
    float a0 = 0.f, a1 = 0.f;
    for (int e = beg; e < end; e++) {
        const float* r = hs + (size_t)col[e] * DIM;
        a0 += r[t];
        if (t < DIM - 256) a1 += r[t + 256];
    }
    float sv = scalev[v];
    float rv = r1row ? r1row[v] : 0.f;

    float v0 = a0 * sv;
    if (bias) v0 += bias[t];
    if (r1row) v0 += rv * r1col[t];
    if (residual) v0 += residual[(size_t)v * DIM + t];

    float v1 = 0.f;
    int t2 = t + 256;
    if (t2 < DIM) {
        v1 = a1 * sv;
        if (bias) v1 += bias[t2];
        if (r1row) v1 += rv * r1col[t2];
        if (residual) v1 += residual[(size_t)v * DIM + t2];
    }

    if (outf) {
        outf[(size_t)v * DIM + t] = v0;
        if (t2 < DIM) outf[(size_t)v * DIM + t2] = v1;
    } else {
        size_t b = (size_t)v * KP;
        unsigned short h0 = f2bf(v0);
        oh[b + t] = h0; ol[b + t] = f2bf(v0 - bf2f(h0));
        if (t2 < KP) {
            float x = (t2 < DIM) ? v1 : 0.f;
            unsigned short h1 = f2bf(x);
            oh[b + t2] = h1; ol[b + t2] = f2bf(x - bf2f(h1));
        }
    }
}

// ---------------------------------------------------------------------------
// Split helpers
// ---------------------------------------------------------------------------
// X [M][300] fp32 row-major -> hi/lo planes [M][KP] (zero-padded)
__global__ void splita_kernel(const float* __restrict__ X,
                              unsigned short* __restrict__ oh, unsigned short* __restrict__ ol)
{
    int v = blockIdx.x;
    int k = threadIdx.x;        // 320 threads
    float x = (k < DIM) ? X[(size_t)v * DIM + k] : 0.f;
    unsigned short h = f2bf(x);
    oh[(size_t)v * KP + k] = h;
    ol[(size_t)v * KP + k] = f2bf(x - bf2f(h));
}

// W [K=300][ncols] fp32 -> transposed planes rows (col0+n): [*][KP]
__global__ void splitw_kernel(const float* __restrict__ W, int ncols, int col0,
                              unsigned short* __restrict__ oh, unsigned short* __restrict__ ol)
{
    int n = blockIdx.x;
    int k = threadIdx.x;        // 320 threads
    float x = (k < DIM) ? W[(size_t)k * ncols + n] : 0.f;
    unsigned short h = f2bf(x);
    oh[(size_t)(col0 + n) * KP + k] = h;
    ol[(size_t)(col0 + n) * KP + k] = f2bf(x - bf2f(h));
}

__global__ void concat3_kernel(const float* __restrict__ a, const float* __restrict__ b,
                               const float* __restrict__ c, float* __restrict__ o)
{
    int t = blockIdx.x * 256 + threadIdx.x;
    if (t >= NQKV) return;
    o[t] = (t < 300) ? a[t] : ((t < 600) ? b[t - 300] : c[t - 600]);
}

// ---------------------------------------------------------------------------
// 30-head attention over 3 views, folded mean over q-positions.
// QKV: [3][cm][900] rows = q|k|v.  Writes om rows [r0, r0+cm).
// ---------------------------------------------------------------------------
__global__ __launch_bounds__(256) void attn_kernel(
    const float* __restrict__ QKV, float* __restrict__ om, int cm, int r0)
{
    int t = blockIdx.x * 256 + threadIdx.x;
    if (t >= cm * 30) return;
    int i = t / 30, h = t - i * 30;
    int off = h * 10;
    float q[3][10], k[3][10], v[3][10];
#pragma unroll
    for (int s = 0; s < 3; s++) {
        const float* base = QKV + ((size_t)s * cm + i) * NQKV;
#pragma unroll
        for (int d = 0; d < 10; d++) {
            q[s][d] = base[off + d];
            k[s][d] = base[300 + off + d];
            v[s][d] = base[600 + off + d];
        }
    }
    const float scale = 0.31622776601683794f;  // 1/sqrt(10)
    float wgt[3] = {0.f, 0.f, 0.f};
#pragma unroll
    for (int qi = 0; qi < 3; qi++) {
        float sc[3];
#pragma unroll
        for (int ki = 0; ki < 3; ki++) {
            float s_ = 0.f;
#pragma unroll
            for (int d = 0; d < 10; d++) s_ = fmaf(q[qi][d], k[ki][d], s_);
            sc[ki] = s_ * scale;
        }
        float m = fmaxf(sc[0], fmaxf(sc[1], sc[2]));
        float e0 = expf(sc[0] - m), e1 = expf(sc[1] - m), e2 = expf(sc[2] - m);
        float inv = 1.f / (e0 + e1 + e2);
        wgt[0] += e0 * inv; wgt[1] += e1 * inv; wgt[2] += e2 * inv;
    }
    float* op = om + (size_t)(r0 + i) * DIM + off;
#pragma unroll
    for (int d = 0; d < 10; d++)
        op[d] = (wgt[0] * v[0][d] + wgt[1] * v[1][d] + wgt[2] * v[2][d]) * (1.f / 3.f);
}

// DM[d,:] = (1/64) * sum over valid tokens of om[idx,:];  DC[d] = cnt/64
__global__ __launch_bounds__(256) void docmean_kernel(
    const float* __restrict__ om, const int* __restrict__ adj,
    float* __restrict__ DM, float* __restrict__ DC)
{
    int d = blockIdx.x;
    int t = threadIdx.x;
    float a0 = 0.f, a1 = 0.f;
    int cnt = 0;
    for (int l = 0; l < DLEN; l++) {
        int idx = adj[d * DLEN + l];
        if (idx < V_NODES) {
            cnt++;
            const float* r = om + (size_t)idx * DIM;
            a0 += r[t];
            if (t < DIM - 256) a1 += r[t + 256];
        }
    }
    DM[(size_t)d * DIM + t] = a0 * (1.f / 64.f);
    if (t < DIM - 256) DM[(size_t)d * DIM + t + 256] = a1 * (1.f / 64.f);
    if (t == 0) DC[d] = (float)cnt * (1.f / 64.f);
}

// ---------------------------------------------------------------------------
extern "C" void kernel_launch(void* const* d_in, const int* in_sizes, int n_in,
                              void* d_out, int out_size, void* d_ws, size_t ws_size,
                              hipStream_t stream)
{
    const int* adj = (const int*)d_in[0];
    const int* srcs[3] = {(const int*)d_in[1], (const int*)d_in[3], (const int*)d_in[5]};
    const int* dsts[3] = {(const int*)d_in[2], (const int*)d_in[4], (const int*)d_in[6]};
    const float* emb = (const float*)d_in[8];
    const float* W1[3] = {(const float*)d_in[9],  (const float*)d_in[13], (const float*)d_in[17]};
    const float* b1[3] = {(const float*)d_in[10], (const float*)d_in[14], (const float*)d_in[18]};
    const float* W2[3] = {(const float*)d_in[11], (const float*)d_in[15], (const float*)d_in[19]};
    const float* b2[3] = {(const float*)d_in[12], (const float*)d_in[16], (const float*)d_in[20]};
    const float* Wq = (const float*)d_in[21], *bq = (const float*)d_in[22];
    const float* Wk = (const float*)d_in[23], *bk = (const float*)d_in[24];
    const float* Wv = (const float*)d_in[25], *bv = (const float*)d_in[26];
    const float* Wo = (const float*)d_in[27], *bo = (const float*)d_in[28];
    const float* Wd = (const float*)d_in[29], *bd = (const float*)d_in[30];
    const float* Wfc = (const float*)d_in[31], *bfc = (const float*)d_in[32];
    float* out = (float*)d_out;

    // ---- workspace carve ----
    char* p = (char*)d_ws;
    auto alloc = [&](size_t bytes) { void* r = (void*)p; p += (bytes + 255) & ~(size_t)255; return r; };
    // QKVc region aliases [embs_hi | embs_lo | Tmid] (allocated first, contiguous)
    unsigned short* embs_hi = (unsigned short*)alloc((size_t)V_NODES * KP * 2);  // 19.2 MB
    unsigned short* embs_lo = (unsigned short*)alloc((size_t)V_NODES * KP * 2);  // 19.2 MB
    float* Tmid = (float*)alloc((size_t)V_NODES * DIM * 4);                      // 36 MB
    float* QKVc = (float*)embs_hi;   // [3][CM][900] fp32 = 64.8 MB <= 74.4 MB

    float* ns   = (float*)alloc(V_NODES * 4);
    float* nd   = (float*)alloc(V_NODES * 4);
    float* ndns = (float*)alloc(V_NODES * 4);
    float* dhat = (float*)alloc(V_NODES * 4);
    int* ibase = (int*)alloc(3 * V_NODES * 4);
    int* deg0 = ibase, *deg1 = ibase + V_NODES, *cursor = ibase + 2 * V_NODES;
    int* row_ptr = (int*)alloc((V_NODES + 1) * 4);
    int* col     = (int*)alloc(NE * 4);

    float* Wdf   = (float*)alloc(300 * 20 * 4);
    float* Wcomb = (float*)alloc(300 * 20 * 4);
    float* v1    = (float*)alloc(20 * 4);
    float* v2    = (float*)alloc(20 * 4);
    float* b1w2  = (float*)alloc(300 * 4);
    float* bqkv  = (float*)alloc(NQKV * 4);
    float* W12   = (float*)alloc(300 * 300 * 4);
    unsigned short* W12t_hi = (unsigned short*)alloc(300 * KP * 2);
    unsigned short* W12t_lo = (unsigned short*)alloc(300 * KP * 2);
    unsigned short* Wqkvt_hi = (unsigned short*)alloc((size_t)NQKV * KP * 2);
    unsigned short* Wqkvt_lo = (unsigned short*)alloc((size_t)NQKV * KP * 2);

    float* T1 = (float*)alloc((size_t)V_NODES * DIM * 4);                        // 36 MB
    unsigned short* Bvs_hi[3];
    unsigned short* Bvs_lo[3];
    for (int i = 0; i < 3; i++) {
        Bvs_hi[i] = (unsigned short*)alloc((size_t)V_NODES * KP * 2);
        Bvs_lo[i] = (unsigned short*)alloc((size_t)V_NODES * KP * 2);
    }
    float* DM = (float*)Bvs_hi[0];   // [NDOCS][300] = 9.8 MB (Bvs free post-QKV)
    float* DC = (float*)Bvs_hi[1];

    auto mgemm = [&](const unsigned short* ah, const unsigned short* al,
                     const unsigned short* bh, const unsigned short* bl,
                     float* C, int M, int N, int ldc,
                     const float* bias, const float* rowscale) {
        dim3 grid((N + GBN - 1) / GBN, (M + GBM - 1) / GBM);
        hipLaunchKernelGGL(mgemm_kernel, grid, dim3(256), 0, stream,
                           ah, al, bh, bl, C, M, N, ldc, bias, rowscale);
    };
    auto sgemm = [&](const float* A, const float* B, float* C, int M, int N, int K,
                     const float* bias, const float* rowv = nullptr, const float* colv = nullptr) {
        dim3 grid((N + BN - 1) / BN, (M + BM - 1) / BM);
        hipLaunchKernelGGL(sgemm_kernel, grid, dim3(256), 0, stream,
                           A, B, C, M, N, K, bias, rowv, colv);
    };

    const int EB = (NE + 255) / 256;
    const int VB = (V_NODES + 255) / 256;

    // ---- one-time prep ----
    sgemm(Wd, Wfc, Wdf, DIM, 20, DIM, nullptr);            // Wd@Wfc
    sgemm(Wo, Wdf, Wcomb, DIM, 20, DIM, nullptr);          // Wo@Wd@Wfc
    sgemm(bo, Wdf, v1, 1, 20, DIM, nullptr);               // bo@Wd@Wfc
    sgemm(bd, Wfc, v2, 1, 20, DIM, bfc);                   // bd@Wfc+bfc
    hipLaunchKernelGGL(concat3_kernel, dim3(4), dim3(256), 0, stream, bq, bk, bv, bqkv);
    hipLaunchKernelGGL(splitw_kernel, dim3(300), dim3(KP), 0, stream, Wq, 300, 0,   Wqkvt_hi, Wqkvt_lo);
    hipLaunchKernelGGL(splitw_kernel, dim3(300), dim3(KP), 0, stream, Wk, 300, 300, Wqkvt_hi, Wqkvt_lo);
    hipLaunchKernelGGL(splitw_kernel, dim3(300), dim3(KP), 0, stream, Wv, 300, 600, Wqkvt_hi, Wqkvt_lo);
    hipLaunchKernelGGL(splita_kernel, dim3(V_NODES), dim3(KP), 0, stream, emb, embs_hi, embs_lo);

    // ---- three GCN branches (two layers folded: Â² X W12 + dhat⊗(b1W2) + b2 + X) ----
    for (int br = 0; br < 3; br++) {
        hipMemsetAsync(ibase, 0, (size_t)3 * V_NODES * 4, stream);
        hipLaunchKernelGGL(degree_kernel, dim3(EB), dim3(256), 0, stream, srcs[br], dsts[br], deg0, deg1, NE);
        hipLaunchKernelGGL(nsnd_kernel, dim3(VB), dim3(256), 0, stream, deg0, deg1, ns, nd, ndns, V_NODES);
        hipLaunchKernelGGL(scan_kernel, dim3(1), dim3(1024), 0, stream, deg1, row_ptr, V_NODES);
        hipLaunchKernelGGL(fill_kernel, dim3(EB), dim3(256), 0, stream, srcs[br], dsts[br], row_ptr, cursor, col, NE);
        hipLaunchKernelGGL(dhat_kernel, dim3(VB), dim3(256), 0, stream, row_ptr, col, ns, nd, dhat, V_NODES);

        sgemm(W1[br], W2[br], W12, DIM, DIM, DIM, nullptr);           // W12 = W1@W2
        sgemm(b1[br], W2[br], b1w2, 1, DIM, DIM, nullptr);            // b1@W2
        hipLaunchKernelGGL(splitw_kernel, dim3(300), dim3(KP), 0, stream, W12, 300, 0, W12t_hi, W12t_lo);

        // T1 = ns ⊙ (emb @ W12)
        mgemm(embs_hi, embs_lo, W12t_hi, W12t_lo, T1, V_NODES, DIM, DIM, nullptr, ns);
        // Tmid = ndns ⊙ A(T1)
        hipLaunchKernelGGL(agg_kernel, dim3(V_NODES), dim3(256), 0, stream,
                           T1, row_ptr, col, ndns, (const float*)nullptr,
                           (const float*)nullptr, (const float*)nullptr, (const float*)nullptr,
                           Tmid, (unsigned short*)nullptr, (unsigned short*)nullptr);
        // Bvs[br] = split( nd ⊙ A(Tmid) + dhat⊗b1w2 + b2 + emb )
        hipLaunchKernelGGL(agg_kernel, dim3(V_NODES), dim3(256), 0, stream,
                           Tmid, row_ptr, col, nd, b2[br], dhat, b1w2, emb,
                           (float*)nullptr, Bvs_hi[br], Bvs_lo[br]);
    }

    // ---- QKV + attention (chunked; QKVc aliases embs/Tmid, both now free) ----
    for (int c = 0; c < V_NODES / CM; c++) {
        int r0 = c * CM;
        for (int s = 0; s < 3; s++) {
            mgemm(Bvs_hi[s] + (size_t)r0 * KP, Bvs_lo[s] + (size_t)r0 * KP,
                  Wqkvt_hi, Wqkvt_lo,
                  QKVc + (size_t)s * CM * NQKV, CM, NQKV, NQKV, bqkv, nullptr);
        }
        hipLaunchKernelGGL(attn_kernel, dim3((CM * 30 + 255) / 256), dim3(256), 0, stream,
                           QKVc, T1, CM, r0);
    }

    // ---- doc pipeline (folded tail) ----
    hipLaunchKernelGGL(docmean_kernel, dim3(NDOCS), dim3(256), 0, stream, T1, adj, DM, DC);
    sgemm(DM, Wcomb, out, NDOCS, 20, DIM, v2, DC, v1);   // out = DM@Wcomb + DC⊗v1 + v2
}